// Round 1
// baseline (1289.565 us; speedup 1.0000x reference)
//
#include <hip/hip_runtime.h>
#include <stdint.h>

#define NREAL   20000
#define NNODES  20001
#define VN      20000
#define E_EDGES 320000
#define NEXP    80004
#define QKV_LD  768

typedef unsigned short u16;
typedef unsigned int   u32;
typedef __bf16 bf16x8 __attribute__((ext_vector_type(8)));
typedef float  f32x4  __attribute__((ext_vector_type(4)));
typedef u16    u16x8  __attribute__((ext_vector_type(8)));

__device__ __forceinline__ float bf2f(u16 v) {
    union { u32 u; float f; } x; x.u = ((u32)v) << 16; return x.f;
}
__device__ __forceinline__ u16 f2bf(float f) {
    union { float f; u32 u; } x; x.f = f;
    u32 r = (x.u + 0x7fffu + ((x.u >> 16) & 1u)) >> 16;
    return (u16)r;
}
__device__ __forceinline__ float4 ld4bf(const u16* p) {
    ushort4 u = *(const ushort4*)p;
    return make_float4(bf2f(u.x), bf2f(u.y), bf2f(u.z), bf2f(u.w));
}
__device__ __forceinline__ u32 enc_f(float f) {
    u32 u = __float_as_uint(f);
    return (u & 0x80000000u) ? ~u : (u | 0x80000000u);
}
__device__ __forceinline__ float dec_f(u32 u) {
    u32 v = (u & 0x80000000u) ? (u & 0x7fffffffu) : ~u;
    return __uint_as_float(v);
}

// ---------------- setup kernels ----------------

__global__ void hinit_kernel(const float* __restrict__ x, float* __restrict__ h,
                             u16* __restrict__ hb) {
    size_t i = (size_t)blockIdx.x * 256 + threadIdx.x;
    if (i >= (size_t)NNODES * 256) return;
    float v = (i < (size_t)NREAL * 256) ? x[i] : 0.0f;
    h[i] = v;
    hb[i] = f2bf(v);
}

__global__ void zero_csr_kernel(int* cnt, int* fill, int* ecnt) {
    int i = blockIdx.x * 256 + threadIdx.x;
    if (i < NREAL) { cnt[i] = 0; fill[i] = 0; }
    if (i < NNODES) ecnt[i] = 0;
}

__global__ void csr_count_kernel(const int* __restrict__ ei, int* __restrict__ cnt) {
    int e = blockIdx.x * 256 + threadIdx.x;
    if (e < E_EDGES) atomicAdd(&cnt[ei[E_EDGES + e]], 1);
}

__global__ void csr_scan_kernel(const int* __restrict__ cnt, int* __restrict__ indptr) {
    __shared__ int ssum[256];
    int t = threadIdx.x;
    int c0 = t * 79;
    int s = 0;
    for (int j = 0; j < 79; j++) {
        int i = c0 + j;
        if (i < NREAL) s += cnt[i];
    }
    ssum[t] = s;
    __syncthreads();
    for (int d2 = 1; d2 < 256; d2 <<= 1) {
        int v = (t >= d2) ? ssum[t - d2] : 0;
        __syncthreads();
        ssum[t] += v;
        __syncthreads();
    }
    int run = (t == 0) ? 0 : ssum[t - 1];
    for (int j = 0; j < 79; j++) {
        int i = c0 + j;
        if (i < NREAL) { indptr[i] = run; run += cnt[i]; }
    }
    if (t == 255) indptr[NREAL] = run;
}

__global__ void csr_scatter_kernel(const int* __restrict__ ei, const int* __restrict__ indptr,
                                   int* __restrict__ fill, int* __restrict__ srcs) {
    int e = blockIdx.x * 256 + threadIdx.x;
    if (e < E_EDGES) {
        int d = ei[E_EDGES + e];
        int pos = indptr[d] + atomicAdd(&fill[d], 1);
        srcs[pos] = ei[e];
    }
}

__global__ void exp_scatter_kernel(const int* __restrict__ eei, int* __restrict__ ecnt,
                                   int* __restrict__ esrcs) {
    int e = blockIdx.x * 256 + threadIdx.x;
    if (e < NEXP) {
        int d = eei[NEXP + e];
        int pos = atomicAdd(&ecnt[d], 1);
        esrcs[d * 4 + pos] = eei[e];
    }
}

// transpose + bf16-convert a K x N weight into N x K
__global__ void wconv_kernel(const float* __restrict__ W, u16* __restrict__ out, int K, int N) {
    int i = blockIdx.x * 256 + threadIdx.x;
    if (i >= K * N) return;
    int k = i / N, n = i - k * N;
    out[(size_t)n * K + k] = f2bf(W[i]);
}

// ---------------- GEMM (bf16 MFMA 16x16x32, 128x128 tile, BK=64) ----------------
// A: M x K bf16 row-major; Bt: Nout x K bf16 row-major (pre-transposed weight)
// EPI: 0 = bias->bf16 store; 1 = bias->f32 store; 2 = bias->gelu->bf16; 3 = bias + resid -> f32 + bf16

template <int EPI>
__global__ __launch_bounds__(256, 2) void gemm_kernel(
    const u16* __restrict__ A, const u16* __restrict__ Bt, const float* __restrict__ bias,
    u16* Cb, float* Cf, const float* resid, int M, int K, int Nout) {
    __shared__ u16 lA[128 * 64];
    __shared__ u16 lB[128 * 64];
    const int tid = threadIdx.x;
    const int w = tid >> 6, lane = tid & 63;
    const int tm = blockIdx.x * 128, tn = blockIdx.y * 128;
    const int lm = lane & 15, q = lane >> 4;
    const int cA = (lane & 7) * 8;
    const int rsub = lane >> 3;

    f32x4 acc[4][4];
#pragma unroll
    for (int a = 0; a < 4; a++)
#pragma unroll
        for (int b = 0; b < 4; b++) acc[a][b] = (f32x4)0.0f;

    const int mo = (w >> 1) * 64, no = (w & 1) * 64;

    for (int k0 = 0; k0 < K; k0 += 64) {
        u16x8 ra[4], rb[4];
#pragma unroll
        for (int i = 0; i < 4; i++) {
            int row = w * 32 + i * 8 + rsub;
            int ga = tm + row;
            if (ga > M - 1) ga = M - 1;
            ra[i] = *(const u16x8*)(A + (size_t)ga * K + k0 + cA);
            int gb = tn + row;
            rb[i] = *(const u16x8*)(Bt + (size_t)gb * K + k0 + cA);
        }
        __syncthreads();
#pragma unroll
        for (int i = 0; i < 4; i++) {
            int row = w * 32 + i * 8 + rsub;
            *(u16x8*)&lA[row * 64 + cA] = ra[i];
            *(u16x8*)&lB[row * 64 + cA] = rb[i];
        }
        __syncthreads();
#pragma unroll
        for (int kk = 0; kk < 64; kk += 32) {
            bf16x8 af[4], bfr[4];
#pragma unroll
            for (int t = 0; t < 4; t++) {
                af[t]  = *(const bf16x8*)&lA[(mo + t * 16 + lm) * 64 + kk + q * 8];
                bfr[t] = *(const bf16x8*)&lB[(no + t * 16 + lm) * 64 + kk + q * 8];
            }
#pragma unroll
            for (int mi = 0; mi < 4; mi++)
#pragma unroll
                for (int ni = 0; ni < 4; ni++)
                    acc[mi][ni] = __builtin_amdgcn_mfma_f32_16x16x32_bf16(
                        af[mi], bfr[ni], acc[mi][ni], 0, 0, 0);
        }
    }

#pragma unroll
    for (int mi = 0; mi < 4; mi++) {
#pragma unroll
        for (int r = 0; r < 4; r++) {
            int grow = tm + mo + mi * 16 + q * 4 + r;
            if (grow >= M) continue;
#pragma unroll
            for (int ni = 0; ni < 4; ni++) {
                int gcol = tn + no + ni * 16 + lm;
                float v = acc[mi][ni][r] + bias[gcol];
                size_t idx = (size_t)grow * Nout + gcol;
                if constexpr (EPI == 0) {
                    Cb[idx] = f2bf(v);
                } else if constexpr (EPI == 1) {
                    Cf[idx] = v;
                } else if constexpr (EPI == 2) {
                    float g = 0.5f * v * (1.0f + erff(v * 0.70710678118654752f));
                    Cb[idx] = f2bf(g);
                } else {
                    float o = resid[idx] + v;
                    Cf[idx] = o;
                    Cb[idx] = f2bf(o);
                }
            }
        }
    }
}

// ---------------- attention ----------------
// One wave per destination node. 4 head-groups of 16 lanes; each lane owns 4 dims.
__global__ void attn_node_kernel(const u16* __restrict__ qkv, const int* __restrict__ indptr,
                                 const int* __restrict__ srcs, int fixed_deg, int add_vn,
                                 int n_nodes, u16* __restrict__ out) {
    int gw = (int)((blockIdx.x * (size_t)blockDim.x + threadIdx.x) >> 6);
    if (gw >= n_nodes) return;
    int lane = threadIdx.x & 63;
    int h = lane >> 4, t = lane & 15;
    int off = h * 64 + t * 4;
    float4 qv = ld4bf(qkv + (size_t)gw * QKV_LD + off);
    int beg, deg;
    if (fixed_deg) { beg = gw * fixed_deg; deg = fixed_deg; }
    else           { beg = indptr[gw]; deg = indptr[gw + 1] - beg; }
    int tot = deg + add_vn;
    float m = -1e30f, l = 0.0f;
    float ax = 0, ay = 0, az = 0, aw = 0;
    for (int e = 0; e < tot; e++) {
        int s = (e < deg) ? srcs[beg + e] : VN;
        float4 kv = ld4bf(qkv + (size_t)s * QKV_LD + 256 + off);
        float p = qv.x * kv.x + qv.y * kv.y + qv.z * kv.z + qv.w * kv.w;
        p += __shfl_xor(p, 1); p += __shfl_xor(p, 2);
        p += __shfl_xor(p, 4); p += __shfl_xor(p, 8);
        float sc = p * 0.125f;
        float mn = fmaxf(m, sc);
        float fold = __expf(m - mn);
        float ee = __expf(sc - mn);
        float4 vv = ld4bf(qkv + (size_t)s * QKV_LD + 512 + off);
        ax = ax * fold + vv.x * ee;
        ay = ay * fold + vv.y * ee;
        az = az * fold + vv.z * ee;
        aw = aw * fold + vv.w * ee;
        l = l * fold + ee;
        m = mn;
    }
    float inv = 1.0f / (l + 1e-16f);
    ushort4 o;
    o.x = f2bf(ax * inv); o.y = f2bf(ay * inv);
    o.z = f2bf(az * inv); o.w = f2bf(aw * inv);
    *(ushort4*)(out + (size_t)gw * 256 + off) = o;
}

// virtual node (dst = VN, sources = all 20000 real nodes), dense 3-phase
__global__ void vn_zero_kernel(float* vnum, float* vden, u32* menc) {
    int t = threadIdx.x;
    vnum[t] = 0.0f;
    if (t < 4) { vden[t] = 0.0f; menc[t] = enc_f(-1e30f); }
}

__global__ void vn_score_kernel(const u16* __restrict__ qkv, float* __restrict__ svn,
                                u32* __restrict__ menc) {
    int lane = threadIdx.x & 63;
    int h = lane >> 4, t = lane & 15;
    int off = h * 64 + t * 4;
    float4 qv = ld4bf(qkv + (size_t)VN * QKV_LD + off);
    int wid = (int)((blockIdx.x * (size_t)blockDim.x + threadIdx.x) >> 6);
    int nw = (gridDim.x * blockDim.x) >> 6;
    float wmax = -1e30f;
    for (int i = wid; i < NREAL; i += nw) {
        float4 kv = ld4bf(qkv + (size_t)i * QKV_LD + 256 + off);
        float p = qv.x * kv.x + qv.y * kv.y + qv.z * kv.z + qv.w * kv.w;
        p += __shfl_xor(p, 1); p += __shfl_xor(p, 2);
        p += __shfl_xor(p, 4); p += __shfl_xor(p, 8);
        float sc = p * 0.125f;
        if (t == 0) svn[i * 4 + h] = sc;
        wmax = fmaxf(wmax, sc);
    }
    if (t == 0) atomicMax(&menc[h], enc_f(wmax));
}

__global__ void vn_accum_kernel(const u16* __restrict__ qkv, const float* __restrict__ svn,
                                const u32* __restrict__ menc, float* __restrict__ vnum,
                                float* __restrict__ vden) {
    int lane = threadIdx.x & 63;
    int h = lane >> 4, t = lane & 15;
    int off = h * 64 + t * 4;
    float m = dec_f(menc[h]);
    int wid = (int)((blockIdx.x * (size_t)blockDim.x + threadIdx.x) >> 6);
    int nw = (gridDim.x * blockDim.x) >> 6;
    float ax = 0, ay = 0, az = 0, aw = 0, l = 0;
    for (int i = wid; i < NREAL; i += nw) {
        float e = __expf(svn[i * 4 + h] - m);
        float4 vv = ld4bf(qkv + (size_t)i * QKV_LD + 512 + off);
        ax += e * vv.x; ay += e * vv.y; az += e * vv.z; aw += e * vv.w;
        l += e;
    }
    atomicAdd(&vnum[off + 0], ax);
    atomicAdd(&vnum[off + 1], ay);
    atomicAdd(&vnum[off + 2], az);
    atomicAdd(&vnum[off + 3], aw);
    if (t == 0) atomicAdd(&vden[h], l);
}

__global__ void vn_final_kernel(const float* __restrict__ vnum, const float* __restrict__ vden,
                                u16* __restrict__ araw) {
    int lane = threadIdx.x;
    int h = lane >> 4;
    float inv = 1.0f / (vden[h] + 1e-16f);
    ushort4 o;
    o.x = f2bf(vnum[lane * 4 + 0] * inv);
    o.y = f2bf(vnum[lane * 4 + 1] * inv);
    o.z = f2bf(vnum[lane * 4 + 2] * inv);
    o.w = f2bf(vnum[lane * 4 + 3] * inv);
    *(ushort4*)(araw + (size_t)VN * 256 + lane * 4) = o;
}

// ---------------- layernorm (fused residual + loc + exp) ----------------
__global__ void ln_kernel(const float* hin, const float* __restrict__ aloc,
                          const float* __restrict__ aexp, const float* __restrict__ g,
                          const float* __restrict__ b, float* hout, u16* __restrict__ hb) {
    int row = blockIdx.x * 4 + (threadIdx.x >> 6);
    if (row >= NNODES) return;
    int lane = threadIdx.x & 63;
    size_t base = (size_t)row * 256 + lane * 4;
    float4 xv = *(const float4*)(hin + base);
    float4 av = *(const float4*)(aloc + base);
    float4 ev = *(const float4*)(aexp + base);
    xv.x += av.x + ev.x; xv.y += av.y + ev.y;
    xv.z += av.z + ev.z; xv.w += av.w + ev.w;
    float s = xv.x + xv.y + xv.z + xv.w;
#pragma unroll
    for (int o = 1; o < 64; o <<= 1) s += __shfl_xor(s, o);
    float mu = s * (1.0f / 256.0f);
    float dx = xv.x - mu, dy = xv.y - mu, dz = xv.z - mu, dw = xv.w - mu;
    float ss = dx * dx + dy * dy + dz * dz + dw * dw;
#pragma unroll
    for (int o = 1; o < 64; o <<= 1) ss += __shfl_xor(ss, o);
    float var = ss * (1.0f / 256.0f);
    float inv = 1.0f / sqrtf(var + 1e-5f);
    float4 gv = *(const float4*)(g + lane * 4);
    float4 bv = *(const float4*)(b + lane * 4);
    float4 y;
    y.x = dx * inv * gv.x + bv.x;
    y.y = dy * inv * gv.y + bv.y;
    y.z = dz * inv * gv.z + bv.z;
    y.w = dw * inv * gv.w + bv.w;
    *(float4*)(hout + base) = y;
    ushort4 o4;
    o4.x = f2bf(y.x); o4.y = f2bf(y.y); o4.z = f2bf(y.z); o4.w = f2bf(y.w);
    *(ushort4*)(hb + base) = o4;
}

// ---------------- host ----------------

extern "C" void kernel_launch(void* const* d_in, const int* in_sizes, int n_in,
                              void* d_out, int out_size, void* d_ws, size_t ws_size,
                              hipStream_t stream) {
    (void)in_sizes; (void)n_in; (void)out_size; (void)ws_size;
    const float* x        = (const float*)d_in[0];
    const int*   ei       = (const int*)d_in[1];
    const int*   eei      = (const int*)d_in[2];
    const float* Wqkv_loc = (const float*)d_in[3];
    const float* bqkv_loc = (const float*)d_in[4];
    const float* Wo_loc   = (const float*)d_in[5];
    const float* bo_loc   = (const float*)d_in[6];
    const float* Wqkv_exp = (const float*)d_in[7];
    const float* bqkv_exp = (const float*)d_in[8];
    const float* Wo_exp   = (const float*)d_in[9];
    const float* bo_exp   = (const float*)d_in[10];
    const float* ln_g     = (const float*)d_in[11];
    const float* ln_b     = (const float*)d_in[12];
    const float* W1       = (const float*)d_in[13];
    const float* b1       = (const float*)d_in[14];
    const float* W2       = (const float*)d_in[15];
    const float* b2       = (const float*)d_in[16];

    char* wsp = (char*)d_ws;
    size_t off = 0;
    auto carve = [&](size_t bytes) -> void* {
        void* p = wsp + off;
        off += (bytes + 255) & ~(size_t)255;
        return p;
    };
    float* h_f   = (float*)carve((size_t)NNODES * 256 * 4);
    u16*   h_b   = (u16*)carve((size_t)NNODES * 256 * 2);
    u16*   qkv   = (u16*)carve((size_t)NNODES * 1024 * 2);  // doubles as FFN mid (stride 1024)
    u16*   araw  = (u16*)carve((size_t)NNODES * 256 * 2);
    float* aloc  = (float*)carve((size_t)NNODES * 256 * 4);
    float* aexp  = (float*)carve((size_t)NNODES * 256 * 4);
    u16*   wbf   = (u16*)carve((size_t)3 * 1048576 * 2);
    int*   cnt   = (int*)carve((size_t)NREAL * 4);
    int*   indptr= (int*)carve((size_t)(NREAL + 1) * 4);
    int*   fill  = (int*)carve((size_t)NREAL * 4);
    int*   srcs  = (int*)carve((size_t)E_EDGES * 4);
    int*   ecnt  = (int*)carve((size_t)NNODES * 4);
    int*   esrcs = (int*)carve((size_t)NNODES * 4 * 4);
    float* svn   = (float*)carve((size_t)NREAL * 4 * 4);
    u32*   menc  = (u32*)carve(4 * 4);
    float* vden  = (float*)carve(4 * 4);
    float* vnum  = (float*)carve(256 * 4);

    hinit_kernel<<<(NNODES * 256 + 255) / 256, 256, 0, stream>>>(x, h_f, h_b);
    zero_csr_kernel<<<(NNODES + 255) / 256, 256, 0, stream>>>(cnt, fill, ecnt);
    csr_count_kernel<<<(E_EDGES + 255) / 256, 256, 0, stream>>>(ei, cnt);
    csr_scan_kernel<<<1, 256, 0, stream>>>(cnt, indptr);
    csr_scatter_kernel<<<(E_EDGES + 255) / 256, 256, 0, stream>>>(ei, indptr, fill, srcs);
    exp_scatter_kernel<<<(NEXP + 255) / 256, 256, 0, stream>>>(eei, ecnt, esrcs);

    for (int l = 0; l < 3; l++) {
        const float* wsrc[6] = {
            Wqkv_loc + (size_t)l * 256 * 768, Wo_loc + (size_t)l * 256 * 256,
            Wqkv_exp + (size_t)l * 256 * 768, Wo_exp + (size_t)l * 256 * 256,
            W1 + (size_t)l * 256 * 1024, W2 + (size_t)l * 1024 * 256};
        const int wk[6] = {256, 256, 256, 256, 256, 1024};
        const int wn[6] = {768, 256, 768, 256, 1024, 256};
        const size_t wo[6] = {0, 196608, 262144, 458752, 524288, 786432};
        for (int m = 0; m < 6; m++) {
            int tot = wk[m] * wn[m];
            wconv_kernel<<<(tot + 255) / 256, 256, 0, stream>>>(
                wsrc[m], wbf + (size_t)l * 1048576 + wo[m], wk[m], wn[m]);
        }
    }

    for (int l = 0; l < 3; l++) {
        const u16* wqkvL = wbf + (size_t)l * 1048576 + 0;
        const u16* woL   = wbf + (size_t)l * 1048576 + 196608;
        const u16* wqkvE = wbf + (size_t)l * 1048576 + 262144;
        const u16* woE   = wbf + (size_t)l * 1048576 + 458752;
        const u16* w1T   = wbf + (size_t)l * 1048576 + 524288;
        const u16* w2T   = wbf + (size_t)l * 1048576 + 786432;

        // local attention branch
        gemm_kernel<0><<<dim3(157, 6), 256, 0, stream>>>(
            h_b, wqkvL, bqkv_loc + l * 768, qkv, nullptr, nullptr, NNODES, 256, 768);
        vn_zero_kernel<<<1, 256, 0, stream>>>(vnum, vden, menc);
        vn_score_kernel<<<80, 256, 0, stream>>>(qkv, svn, menc);
        vn_accum_kernel<<<80, 256, 0, stream>>>(qkv, svn, menc, vnum, vden);
        vn_final_kernel<<<1, 64, 0, stream>>>(vnum, vden, araw);
        attn_node_kernel<<<5000, 256, 0, stream>>>(qkv, indptr, srcs, 0, 1, NREAL, araw);
        gemm_kernel<1><<<dim3(157, 2), 256, 0, stream>>>(
            araw, woL, bo_loc + l * 256, nullptr, aloc, nullptr, NNODES, 256, 256);

        // expander attention branch
        gemm_kernel<0><<<dim3(157, 6), 256, 0, stream>>>(
            h_b, wqkvE, bqkv_exp + l * 768, qkv, nullptr, nullptr, NNODES, 256, 768);
        attn_node_kernel<<<5001, 256, 0, stream>>>(qkv, nullptr, esrcs, 4, 0, NNODES, araw);
        gemm_kernel<1><<<dim3(157, 2), 256, 0, stream>>>(
            araw, woE, bo_exp + l * 256, nullptr, aexp, nullptr, NNODES, 256, 256);

        // layernorm(res + loc + exp)
        ln_kernel<<<(NNODES + 3) / 4, 256, 0, stream>>>(
            h_f, aloc, aexp, ln_g + l * 256, ln_b + l * 256, h_f, h_b);

        // FFN: mid = gelu(h@W1+b1) [bf16, stride 1024 in qkv buffer]; h += mid@W2+b2
        gemm_kernel<2><<<dim3(157, 8), 256, 0, stream>>>(
            h_b, w1T, b1 + l * 1024, qkv, nullptr, nullptr, NNODES, 256, 1024);
        gemm_kernel<3><<<dim3(157, 2), 256, 0, stream>>>(
            qkv, w2T, b2 + l * 256, h_b, h_f, h_f, NNODES, 1024, 256);
    }

    hipMemcpyAsync(d_out, h_f, (size_t)NREAL * 256 * 4, hipMemcpyDeviceToDevice, stream);
}

// Round 2
// 1274.586 us; speedup vs baseline: 1.0118x; 1.0118x over previous
//
#include <hip/hip_runtime.h>
#include <stdint.h>

#define NREAL   20000
#define NNODES  20001
#define VN      20000
#define E_EDGES 320000
#define NEXP    80004
#define QKV_LD  768

typedef unsigned short u16;
typedef unsigned int   u32;
typedef __bf16 bf16x8 __attribute__((ext_vector_type(8)));
typedef float  f32x4  __attribute__((ext_vector_type(4)));

__device__ __forceinline__ float bf2f(u16 v) {
    union { u32 u; float f; } x; x.u = ((u32)v) << 16; return x.f;
}
__device__ __forceinline__ u16 f2bf(float f) {
    union { float f; u32 u; } x; x.f = f;
    u32 r = (x.u + 0x7fffu + ((x.u >> 16) & 1u)) >> 16;
    return (u16)r;
}
__device__ __forceinline__ float4 ld4bf(const u16* p) {
    ushort4 u = *(const ushort4*)p;
    return make_float4(bf2f(u.x), bf2f(u.y), bf2f(u.z), bf2f(u.w));
}
__device__ __forceinline__ u32 enc_f(float f) {
    u32 u = __float_as_uint(f);
    return (u & 0x80000000u) ? ~u : (u | 0x80000000u);
}
__device__ __forceinline__ float dec_f(u32 u) {
    u32 v = (u & 0x80000000u) ? (u & 0x7fffffffu) : ~u;
    return __uint_as_float(v);
}

#define GLOAD_LDS16(g, l) __builtin_amdgcn_global_load_lds( \
    (const __attribute__((address_space(1))) void*)(g),      \
    (__attribute__((address_space(3))) void*)(l), 16, 0, 0)

// ---------------- setup kernels ----------------

__global__ void hinit_kernel(const float* __restrict__ x, float* __restrict__ h,
                             u16* __restrict__ hb) {
    size_t i = (size_t)blockIdx.x * 256 + threadIdx.x;
    if (i >= (size_t)NNODES * 256) return;
    float v = (i < (size_t)NREAL * 256) ? x[i] : 0.0f;
    h[i] = v;
    hb[i] = f2bf(v);
}

__global__ void zero_csr_kernel(int* cnt, int* fill, int* ecnt) {
    int i = blockIdx.x * 256 + threadIdx.x;
    if (i < NREAL) { cnt[i] = 0; fill[i] = 0; }
    if (i < NNODES) ecnt[i] = 0;
}

__global__ void csr_count_kernel(const int* __restrict__ ei, int* __restrict__ cnt) {
    int e = blockIdx.x * 256 + threadIdx.x;
    if (e < E_EDGES) atomicAdd(&cnt[ei[E_EDGES + e]], 1);
}

__global__ void csr_scan_kernel(const int* __restrict__ cnt, int* __restrict__ indptr) {
    __shared__ int ssum[256];
    int t = threadIdx.x;
    int c0 = t * 79;
    int s = 0;
    for (int j = 0; j < 79; j++) {
        int i = c0 + j;
        if (i < NREAL) s += cnt[i];
    }
    ssum[t] = s;
    __syncthreads();
    for (int d2 = 1; d2 < 256; d2 <<= 1) {
        int v = (t >= d2) ? ssum[t - d2] : 0;
        __syncthreads();
        ssum[t] += v;
        __syncthreads();
    }
    int run = (t == 0) ? 0 : ssum[t - 1];
    for (int j = 0; j < 79; j++) {
        int i = c0 + j;
        if (i < NREAL) { indptr[i] = run; run += cnt[i]; }
    }
    if (t == 255) indptr[NREAL] = run;
}

__global__ void csr_scatter_kernel(const int* __restrict__ ei, const int* __restrict__ indptr,
                                   int* __restrict__ fill, int* __restrict__ srcs) {
    int e = blockIdx.x * 256 + threadIdx.x;
    if (e < E_EDGES) {
        int d = ei[E_EDGES + e];
        int pos = indptr[d] + atomicAdd(&fill[d], 1);
        srcs[pos] = ei[e];
    }
}

__global__ void exp_scatter_kernel(const int* __restrict__ eei, int* __restrict__ ecnt,
                                   int* __restrict__ esrcs) {
    int e = blockIdx.x * 256 + threadIdx.x;
    if (e < NEXP) {
        int d = eei[NEXP + e];
        int pos = atomicAdd(&ecnt[d], 1);
        esrcs[d * 4 + pos] = eei[e];
    }
}

// transpose + bf16-convert a K x N weight into N x K
__global__ void wconv_kernel(const float* __restrict__ W, u16* __restrict__ out, int K, int N) {
    int i = blockIdx.x * 256 + threadIdx.x;
    if (i >= K * N) return;
    int k = i / N, n = i - k * N;
    out[(size_t)n * K + k] = f2bf(W[i]);
}

// ---------------- GEMM (bf16 MFMA 16x16x32, 128x128 tile, BK=64, global_load_lds) ----------------
// A: M x K bf16 row-major; Bt: Nout x K bf16 row-major (pre-transposed weight)
// EPI: 0 = bias->bf16; 1 = bias->f32; 2 = bias->gelu->bf16; 3 = bias+resid->f32+bf16;
//      4 = bias+resid->f32 (rows < NREAL only; final output)

template <int EPI>
__global__ __launch_bounds__(256, 2) void gemm_kernel(
    const u16* __restrict__ A, const u16* __restrict__ Bt, const float* __restrict__ bias,
    u16* Cb, float* Cf, const float* resid, int M, int K, int Nout) {
    __shared__ u16 lA[128 * 64];
    __shared__ u16 lB[128 * 64];
    const int tid = threadIdx.x;
    const int w = tid >> 6, lane = tid & 63;
    const int tm = blockIdx.x * 128, tn = blockIdx.y * 128;
    const int lm = lane & 15, q = lane >> 4;
    const int c8 = (lane & 7) * 8;   // element column within 64-wide chunk
    const int r8 = lane >> 3;        // row within 8-row chunk

    f32x4 acc[4][4];
#pragma unroll
    for (int a = 0; a < 4; a++)
#pragma unroll
        for (int b = 0; b < 4; b++) acc[a][b] = (f32x4)0.0f;

    const int mo = (w >> 1) * 64, no = (w & 1) * 64;

    int arow[4], brow[4];
#pragma unroll
    for (int i = 0; i < 4; i++) {
        int row = w * 32 + i * 8 + r8;
        int ga = tm + row;
        arow[i] = (ga > M - 1) ? (M - 1) : ga;
        brow[i] = tn + row;          // Nout is always a multiple of 128
    }

    for (int k0 = 0; k0 < K; k0 += 64) {
#pragma unroll
        for (int i = 0; i < 4; i++) {
            GLOAD_LDS16(A + (size_t)arow[i] * K + k0 + c8, &lA[(w * 32 + i * 8) * 64]);
            GLOAD_LDS16(Bt + (size_t)brow[i] * K + k0 + c8, &lB[(w * 32 + i * 8) * 64]);
        }
        __syncthreads();
#pragma unroll
        for (int kk = 0; kk < 64; kk += 32) {
            bf16x8 af[4], bfr[4];
#pragma unroll
            for (int t = 0; t < 4; t++) {
                af[t]  = *(const bf16x8*)&lA[(mo + t * 16 + lm) * 64 + kk + q * 8];
                bfr[t] = *(const bf16x8*)&lB[(no + t * 16 + lm) * 64 + kk + q * 8];
            }
#pragma unroll
            for (int mi = 0; mi < 4; mi++)
#pragma unroll
                for (int ni = 0; ni < 4; ni++)
                    acc[mi][ni] = __builtin_amdgcn_mfma_f32_16x16x32_bf16(
                        af[mi], bfr[ni], acc[mi][ni], 0, 0, 0);
        }
        __syncthreads();
    }

#pragma unroll
    for (int mi = 0; mi < 4; mi++) {
#pragma unroll
        for (int r = 0; r < 4; r++) {
            int grow = tm + mo + mi * 16 + q * 4 + r;
            if (grow >= M) continue;
#pragma unroll
            for (int ni = 0; ni < 4; ni++) {
                int gcol = tn + no + ni * 16 + lm;
                float v = acc[mi][ni][r] + bias[gcol];
                size_t idx = (size_t)grow * Nout + gcol;
                if constexpr (EPI == 0) {
                    Cb[idx] = f2bf(v);
                } else if constexpr (EPI == 1) {
                    Cf[idx] = v;
                } else if constexpr (EPI == 2) {
                    float g = 0.5f * v * (1.0f + erff(v * 0.70710678118654752f));
                    Cb[idx] = f2bf(g);
                } else if constexpr (EPI == 3) {
                    float o = resid[idx] + v;
                    Cf[idx] = o;
                    Cb[idx] = f2bf(o);
                } else {
                    if (grow < NREAL) {
                        float o = resid[idx] + v;
                        Cf[idx] = o;
                    }
                }
            }
        }
    }
}

// ---------------- attention ----------------
// One wave per destination node. 4 head-groups of 16 lanes; each lane owns 4 dims.
// 2-way edge unroll: both K/V pairs in flight before the online-softmax update.
__global__ void attn_node_kernel(const u16* __restrict__ qkv, const int* __restrict__ indptr,
                                 const int* __restrict__ srcs, int fixed_deg, int add_vn,
                                 int n_nodes, u16* __restrict__ out) {
    int gw = (int)((blockIdx.x * (size_t)blockDim.x + threadIdx.x) >> 6);
    if (gw >= n_nodes) return;
    int lane = threadIdx.x & 63;
    int h = lane >> 4, t = lane & 15;
    int off = h * 64 + t * 4;
    float4 qv = ld4bf(qkv + (size_t)gw * QKV_LD + off);
    int beg, deg;
    if (fixed_deg) { beg = gw * fixed_deg; deg = fixed_deg; }
    else           { beg = indptr[gw]; deg = indptr[gw + 1] - beg; }
    int tot = deg + add_vn;
    float m = -1e30f, l = 0.0f;
    float ax = 0, ay = 0, az = 0, aw = 0;
    int e = 0;
    for (; e + 2 <= tot; e += 2) {
        int s0 = (e < deg) ? srcs[beg + e] : VN;
        int s1 = (e + 1 < deg) ? srcs[beg + e + 1] : VN;
        const u16* p0 = qkv + (size_t)s0 * QKV_LD + off;
        const u16* p1 = qkv + (size_t)s1 * QKV_LD + off;
        float4 k0 = ld4bf(p0 + 256);
        float4 k1 = ld4bf(p1 + 256);
        float4 v0 = ld4bf(p0 + 512);
        float4 v1 = ld4bf(p1 + 512);
        float pa = qv.x * k0.x + qv.y * k0.y + qv.z * k0.z + qv.w * k0.w;
        float pb = qv.x * k1.x + qv.y * k1.y + qv.z * k1.z + qv.w * k1.w;
        pa += __shfl_xor(pa, 1); pb += __shfl_xor(pb, 1);
        pa += __shfl_xor(pa, 2); pb += __shfl_xor(pb, 2);
        pa += __shfl_xor(pa, 4); pb += __shfl_xor(pb, 4);
        pa += __shfl_xor(pa, 8); pb += __shfl_xor(pb, 8);
        float sa = pa * 0.125f, sb = pb * 0.125f;
        float mn = fmaxf(m, fmaxf(sa, sb));
        float fold = __expf(m - mn);
        float e0 = __expf(sa - mn);
        float e1 = __expf(sb - mn);
        ax = ax * fold + v0.x * e0 + v1.x * e1;
        ay = ay * fold + v0.y * e0 + v1.y * e1;
        az = az * fold + v0.z * e0 + v1.z * e1;
        aw = aw * fold + v0.w * e0 + v1.w * e1;
        l = l * fold + e0 + e1;
        m = mn;
    }
    if (e < tot) {
        int s = (e < deg) ? srcs[beg + e] : VN;
        const u16* p = qkv + (size_t)s * QKV_LD + off;
        float4 kv = ld4bf(p + 256);
        float4 vv = ld4bf(p + 512);
        float p0 = qv.x * kv.x + qv.y * kv.y + qv.z * kv.z + qv.w * kv.w;
        p0 += __shfl_xor(p0, 1); p0 += __shfl_xor(p0, 2);
        p0 += __shfl_xor(p0, 4); p0 += __shfl_xor(p0, 8);
        float sc = p0 * 0.125f;
        float mn = fmaxf(m, sc);
        float fold = __expf(m - mn);
        float ee = __expf(sc - mn);
        ax = ax * fold + vv.x * ee;
        ay = ay * fold + vv.y * ee;
        az = az * fold + vv.z * ee;
        aw = aw * fold + vv.w * ee;
        l = l * fold + ee;
        m = mn;
    }
    float inv = 1.0f / (l + 1e-16f);
    ushort4 o;
    o.x = f2bf(ax * inv); o.y = f2bf(ay * inv);
    o.z = f2bf(az * inv); o.w = f2bf(aw * inv);
    *(ushort4*)(out + (size_t)gw * 256 + off) = o;
}

// virtual node (dst = VN, sources = all 20000 real nodes), dense 3-phase
__global__ void vn_zero_kernel(float* vnum, float* vden, u32* menc) {
    int t = threadIdx.x;
    vnum[t] = 0.0f;
    if (t < 4) { vden[t] = 0.0f; menc[t] = enc_f(-1e30f); }
}

__global__ void vn_score_kernel(const u16* __restrict__ qkv, float* __restrict__ svn,
                                u32* __restrict__ menc) {
    int lane = threadIdx.x & 63;
    int h = lane >> 4, t = lane & 15;
    int off = h * 64 + t * 4;
    float4 qv = ld4bf(qkv + (size_t)VN * QKV_LD + off);
    int wid = (int)((blockIdx.x * (size_t)blockDim.x + threadIdx.x) >> 6);
    int nw = (gridDim.x * blockDim.x) >> 6;
    float wmax = -1e30f;
    for (int i = wid; i < NREAL; i += nw) {
        float4 kv = ld4bf(qkv + (size_t)i * QKV_LD + 256 + off);
        float p = qv.x * kv.x + qv.y * kv.y + qv.z * kv.z + qv.w * kv.w;
        p += __shfl_xor(p, 1); p += __shfl_xor(p, 2);
        p += __shfl_xor(p, 4); p += __shfl_xor(p, 8);
        float sc = p * 0.125f;
        if (t == 0) svn[i * 4 + h] = sc;
        wmax = fmaxf(wmax, sc);
    }
    if (t == 0) atomicMax(&menc[h], enc_f(wmax));
}

__global__ void vn_accum_kernel(const u16* __restrict__ qkv, const float* __restrict__ svn,
                                const u32* __restrict__ menc, float* __restrict__ vnum,
                                float* __restrict__ vden) {
    int lane = threadIdx.x & 63;
    int h = lane >> 4, t = lane & 15;
    int off = h * 64 + t * 4;
    float m = dec_f(menc[h]);
    int wid = (int)((blockIdx.x * (size_t)blockDim.x + threadIdx.x) >> 6);
    int nw = (gridDim.x * blockDim.x) >> 6;
    float ax = 0, ay = 0, az = 0, aw = 0, l = 0;
    for (int i = wid; i < NREAL; i += nw) {
        float e = __expf(svn[i * 4 + h] - m);
        float4 vv = ld4bf(qkv + (size_t)i * QKV_LD + 512 + off);
        ax += e * vv.x; ay += e * vv.y; az += e * vv.z; aw += e * vv.w;
        l += e;
    }
    atomicAdd(&vnum[off + 0], ax);
    atomicAdd(&vnum[off + 1], ay);
    atomicAdd(&vnum[off + 2], az);
    atomicAdd(&vnum[off + 3], aw);
    if (t == 0) atomicAdd(&vden[h], l);
}

__global__ void vn_final_kernel(const float* __restrict__ vnum, const float* __restrict__ vden,
                                u16* __restrict__ araw) {
    int lane = threadIdx.x;
    int h = lane >> 4;
    float inv = 1.0f / (vden[h] + 1e-16f);
    ushort4 o;
    o.x = f2bf(vnum[lane * 4 + 0] * inv);
    o.y = f2bf(vnum[lane * 4 + 1] * inv);
    o.z = f2bf(vnum[lane * 4 + 2] * inv);
    o.w = f2bf(vnum[lane * 4 + 3] * inv);
    *(ushort4*)(araw + (size_t)VN * 256 + lane * 4) = o;
}

// ---------------- layernorm (fused residual + loc + exp) ----------------
__global__ void ln_kernel(const float* hin, const float* __restrict__ aloc,
                          const float* __restrict__ aexp, const float* __restrict__ g,
                          const float* __restrict__ b, float* hout, u16* __restrict__ hb) {
    int row = blockIdx.x * 4 + (threadIdx.x >> 6);
    if (row >= NNODES) return;
    int lane = threadIdx.x & 63;
    size_t base = (size_t)row * 256 + lane * 4;
    float4 xv = *(const float4*)(hin + base);
    float4 av = *(const float4*)(aloc + base);
    float4 ev = *(const float4*)(aexp + base);
    xv.x += av.x + ev.x; xv.y += av.y + ev.y;
    xv.z += av.z + ev.z; xv.w += av.w + ev.w;
    float s = xv.x + xv.y + xv.z + xv.w;
#pragma unroll
    for (int o = 1; o < 64; o <<= 1) s += __shfl_xor(s, o);
    float mu = s * (1.0f / 256.0f);
    float dx = xv.x - mu, dy = xv.y - mu, dz = xv.z - mu, dw = xv.w - mu;
    float ss = dx * dx + dy * dy + dz * dz + dw * dw;
#pragma unroll
    for (int o = 1; o < 64; o <<= 1) ss += __shfl_xor(ss, o);
    float var = ss * (1.0f / 256.0f);
    float inv = 1.0f / sqrtf(var + 1e-5f);
    float4 gv = *(const float4*)(g + lane * 4);
    float4 bv = *(const float4*)(b + lane * 4);
    float4 y;
    y.x = dx * inv * gv.x + bv.x;
    y.y = dy * inv * gv.y + bv.y;
    y.z = dz * inv * gv.z + bv.z;
    y.w = dw * inv * gv.w + bv.w;
    *(float4*)(hout + base) = y;
    ushort4 o4;
    o4.x = f2bf(y.x); o4.y = f2bf(y.y); o4.z = f2bf(y.z); o4.w = f2bf(y.w);
    *(ushort4*)(hb + base) = o4;
}

// ---------------- host ----------------

extern "C" void kernel_launch(void* const* d_in, const int* in_sizes, int n_in,
                              void* d_out, int out_size, void* d_ws, size_t ws_size,
                              hipStream_t stream) {
    (void)in_sizes; (void)n_in; (void)out_size; (void)ws_size;
    const float* x        = (const float*)d_in[0];
    const int*   ei       = (const int*)d_in[1];
    const int*   eei      = (const int*)d_in[2];
    const float* Wqkv_loc = (const float*)d_in[3];
    const float* bqkv_loc = (const float*)d_in[4];
    const float* Wo_loc   = (const float*)d_in[5];
    const float* bo_loc   = (const float*)d_in[6];
    const float* Wqkv_exp = (const float*)d_in[7];
    const float* bqkv_exp = (const float*)d_in[8];
    const float* Wo_exp   = (const float*)d_in[9];
    const float* bo_exp   = (const float*)d_in[10];
    const float* ln_g     = (const float*)d_in[11];
    const float* ln_b     = (const float*)d_in[12];
    const float* W1       = (const float*)d_in[13];
    const float* b1       = (const float*)d_in[14];
    const float* W2       = (const float*)d_in[15];
    const float* b2       = (const float*)d_in[16];

    char* wsp = (char*)d_ws;
    size_t off = 0;
    auto carve = [&](size_t bytes) -> void* {
        void* p = wsp + off;
        off += (bytes + 255) & ~(size_t)255;
        return p;
    };
    float* h_f   = (float*)carve((size_t)NNODES * 256 * 4);
    u16*   h_b   = (u16*)carve((size_t)NNODES * 256 * 2);
    u16*   qkv   = (u16*)carve((size_t)NNODES * 1024 * 2);  // doubles as FFN mid (stride 1024)
    u16*   araw  = (u16*)carve((size_t)NNODES * 256 * 2);
    float* aloc  = (float*)carve((size_t)NNODES * 256 * 4);
    float* aexp  = (float*)carve((size_t)NNODES * 256 * 4);
    u16*   wbf   = (u16*)carve((size_t)3 * 1048576 * 2);
    int*   cnt   = (int*)carve((size_t)NREAL * 4);
    int*   indptr= (int*)carve((size_t)(NREAL + 1) * 4);
    int*   fill  = (int*)carve((size_t)NREAL * 4);
    int*   srcs  = (int*)carve((size_t)E_EDGES * 4);
    int*   ecnt  = (int*)carve((size_t)NNODES * 4);
    int*   esrcs = (int*)carve((size_t)NNODES * 4 * 4);
    float* svn   = (float*)carve((size_t)NREAL * 4 * 4);
    u32*   menc  = (u32*)carve(4 * 4);
    float* vden  = (float*)carve(4 * 4);
    float* vnum  = (float*)carve(256 * 4);

    hinit_kernel<<<(NNODES * 256 + 255) / 256, 256, 0, stream>>>(x, h_f, h_b);
    zero_csr_kernel<<<(NNODES + 255) / 256, 256, 0, stream>>>(cnt, fill, ecnt);
    csr_count_kernel<<<(E_EDGES + 255) / 256, 256, 0, stream>>>(ei, cnt);
    csr_scan_kernel<<<1, 256, 0, stream>>>(cnt, indptr);
    csr_scatter_kernel<<<(E_EDGES + 255) / 256, 256, 0, stream>>>(ei, indptr, fill, srcs);
    exp_scatter_kernel<<<(NEXP + 255) / 256, 256, 0, stream>>>(eei, ecnt, esrcs);

    for (int l = 0; l < 3; l++) {
        const float* wsrc[6] = {
            Wqkv_loc + (size_t)l * 256 * 768, Wo_loc + (size_t)l * 256 * 256,
            Wqkv_exp + (size_t)l * 256 * 768, Wo_exp + (size_t)l * 256 * 256,
            W1 + (size_t)l * 256 * 1024, W2 + (size_t)l * 1024 * 256};
        const int wk[6] = {256, 256, 256, 256, 256, 1024};
        const int wn[6] = {768, 256, 768, 256, 1024, 256};
        const size_t wo[6] = {0, 196608, 262144, 458752, 524288, 786432};
        for (int m = 0; m < 6; m++) {
            int tot = wk[m] * wn[m];
            wconv_kernel<<<(tot + 255) / 256, 256, 0, stream>>>(
                wsrc[m], wbf + (size_t)l * 1048576 + wo[m], wk[m], wn[m]);
        }
    }

    for (int l = 0; l < 3; l++) {
        const u16* wqkvL = wbf + (size_t)l * 1048576 + 0;
        const u16* woL   = wbf + (size_t)l * 1048576 + 196608;
        const u16* wqkvE = wbf + (size_t)l * 1048576 + 262144;
        const u16* woE   = wbf + (size_t)l * 1048576 + 458752;
        const u16* w1T   = wbf + (size_t)l * 1048576 + 524288;
        const u16* w2T   = wbf + (size_t)l * 1048576 + 786432;

        // local attention branch
        gemm_kernel<0><<<dim3(157, 6), 256, 0, stream>>>(
            h_b, wqkvL, bqkv_loc + l * 768, qkv, nullptr, nullptr, NNODES, 256, 768);
        vn_zero_kernel<<<1, 256, 0, stream>>>(vnum, vden, menc);
        vn_score_kernel<<<80, 256, 0, stream>>>(qkv, svn, menc);
        vn_accum_kernel<<<80, 256, 0, stream>>>(qkv, svn, menc, vnum, vden);
        vn_final_kernel<<<1, 64, 0, stream>>>(vnum, vden, araw);
        attn_node_kernel<<<5000, 256, 0, stream>>>(qkv, indptr, srcs, 0, 1, NREAL, araw);
        gemm_kernel<1><<<dim3(157, 2), 256, 0, stream>>>(
            araw, woL, bo_loc + l * 256, nullptr, aloc, nullptr, NNODES, 256, 256);

        // expander attention branch
        gemm_kernel<0><<<dim3(157, 6), 256, 0, stream>>>(
            h_b, wqkvE, bqkv_exp + l * 768, qkv, nullptr, nullptr, NNODES, 256, 768);
        attn_node_kernel<<<5001, 256, 0, stream>>>(qkv, nullptr, esrcs, 4, 0, NNODES, araw);
        gemm_kernel<1><<<dim3(157, 2), 256, 0, stream>>>(
            araw, woE, bo_exp + l * 256, nullptr, aexp, nullptr, NNODES, 256, 256);

        // layernorm(res + loc + exp)
        ln_kernel<<<(NNODES + 3) / 4, 256, 0, stream>>>(
            h_f, aloc, aexp, ln_g + l * 256, ln_b + l * 256, h_f, h_b);

        // FFN: mid = gelu(h@W1+b1) [bf16, stride 1024 in qkv buffer]; h += mid@W2+b2
        gemm_kernel<2><<<dim3(157, 8), 256, 0, stream>>>(
            h_b, w1T, b1 + l * 1024, qkv, nullptr, nullptr, NNODES, 256, 1024);
        if (l < 2) {
            gemm_kernel<3><<<dim3(157, 2), 256, 0, stream>>>(
                qkv, w2T, b2 + l * 256, h_b, h_f, h_f, NNODES, 1024, 256);
        } else {
            gemm_kernel<4><<<dim3(157, 2), 256, 0, stream>>>(
                qkv, w2T, b2 + l * 256, nullptr, (float*)d_out, h_f, NNODES, 1024, 256);
        }
    }
}